// Round 5
// baseline (965.251 us; speedup 1.0000x reference)
//
#include <hip/hip_runtime.h>
#include <hip/hip_bf16.h>

#define LRELU(v) ((v) >= 0.f ? (v) : 0.1f*(v))

typedef float  f32x4 __attribute__((ext_vector_type(4)));
typedef short  s16x8 __attribute__((ext_vector_type(8)));
typedef int    i32x4 __attribute__((ext_vector_type(4)));
typedef unsigned short ushort_t;
typedef unsigned int   u32;

constexpr float GNORM = 1.0f/127.0f;  // dinv[src]*dinv[dst] on complete graph

#define MFMA(d, a, b) d = __builtin_amdgcn_mfma_f32_16x16x32_bf16(a, b, d, 0, 0, 0)

__device__ __forceinline__ ushort_t f2bf(float v) {
    return __builtin_bit_cast(ushort_t, __float2bfloat16(v));
}
__device__ __forceinline__ float bf2f(ushort_t u) {
    return __builtin_bit_cast(float, (u32)u << 16);
}

// ---------------------------------------------------------------------------
// K1: GCN closed form (complete graph): out_v = (S - (hW)_v)/127 + b
// one WG per graph, 256 threads: thread (v = tid&127, hf = tid>>7) owns half
// the output columns of node v.
// ---------------------------------------------------------------------------
__global__ __launch_bounds__(256) void k_gcn(
    const float* __restrict__ x,
    const float* __restrict__ Wg0, const float* __restrict__ bg0,
    const float* __restrict__ Wg1, const float* __restrict__ bg1,
    const float* __restrict__ Wg2, const float* __restrict__ bg2,
    float* __restrict__ hout)
{
    __shared__ __align__(16) float w0[192], w1[1024], w2[2048];
    __shared__ float bb0[32], bb1[32], bb2[64];
    __shared__ float ta[128][33];
    __shared__ float tc[128][65];
    __shared__ float part[8][64];
    __shared__ float S[64];
    const int tid = threadIdx.x;
    const int v = tid & 127, hf = tid >> 7;
    const int b = blockIdx.x;

    for (int idx = tid; idx < 192;  idx += 256) w0[idx] = Wg0[idx];
    for (int idx = tid; idx < 1024; idx += 256) w1[idx] = Wg1[idx];
    for (int idx = tid; idx < 2048; idx += 256) w2[idx] = Wg2[idx];
    if (tid < 32) { bb0[tid] = bg0[tid]; bb1[tid] = bg1[tid]; }
    if (tid >= 64 && tid < 128) bb2[tid-64] = bg2[tid-64];

    float xv[6];
    #pragma unroll
    for (int k = 0; k < 6; ++k) xv[k] = x[(b*128 + v)*6 + k];
    __syncthreads();

    const int rg = tid >> 5, rd = tid & 31;     // 32-col reduction mapping
    const int rg2 = tid >> 6, rd2 = tid & 63;   // 64-col reduction mapping

    // ---- layer 0: 6 -> 32 ----
    float t0[16];
    #pragma unroll
    for (int n = 0; n < 16; ++n) {
        float a = 0.f;
        #pragma unroll
        for (int k = 0; k < 6; ++k) a += xv[k]*w0[k*32 + hf*16 + n];
        t0[n] = a; ta[v][hf*16+n] = a;
    }
    __syncthreads();
    { float p = 0.f;
      for (int r = 0; r < 16; ++r) p += ta[rg*16+r][rd];
      part[rg][rd] = p; }
    __syncthreads();
    if (tid < 32) S[tid] = part[0][tid]+part[1][tid]+part[2][tid]+part[3][tid]
                          +part[4][tid]+part[5][tid]+part[6][tid]+part[7][tid];
    __syncthreads();
    float h1[16];
    #pragma unroll
    for (int n = 0; n < 16; ++n) {
        float hv = (S[hf*16+n] - t0[n])*GNORM + bb0[hf*16+n];
        h1[n] = LRELU(hv);
        ta[v][hf*16+n] = h1[n];
    }
    __syncthreads();

    // ---- layer 1: 32 -> 32 ----
    float t1[16];
    #pragma unroll
    for (int n = 0; n < 16; ++n) t1[n] = 0.f;
    for (int k = 0; k < 32; ++k) {
        const float hk = ta[v][k];
        #pragma unroll
        for (int n4 = 0; n4 < 4; ++n4) {
            const float4 w = *(const float4*)&w1[k*32 + hf*16 + n4*4];
            t1[n4*4+0] += hk*w.x; t1[n4*4+1] += hk*w.y;
            t1[n4*4+2] += hk*w.z; t1[n4*4+3] += hk*w.w;
        }
    }
    __syncthreads();   // all h1 reads done
    #pragma unroll
    for (int n = 0; n < 16; ++n) ta[v][hf*16+n] = t1[n];
    __syncthreads();
    { float p = 0.f;
      for (int r = 0; r < 16; ++r) p += ta[rg*16+r][rd];
      part[rg][rd] = p; }
    __syncthreads();
    if (tid < 32) S[tid] = part[0][tid]+part[1][tid]+part[2][tid]+part[3][tid]
                          +part[4][tid]+part[5][tid]+part[6][tid]+part[7][tid];
    __syncthreads();
    float h2[16];
    #pragma unroll
    for (int n = 0; n < 16; ++n) {
        float hv = (S[hf*16+n] - t1[n])*GNORM + bb1[hf*16+n];
        h2[n] = LRELU(hv);
        ta[v][hf*16+n] = h2[n];
    }
    __syncthreads();

    // ---- layer 2: 32 -> 64 ----
    float t2[32];
    #pragma unroll
    for (int n = 0; n < 32; ++n) t2[n] = 0.f;
    for (int k = 0; k < 32; ++k) {
        const float hk = ta[v][k];
        #pragma unroll
        for (int n4 = 0; n4 < 8; ++n4) {
            const float4 w = *(const float4*)&w2[k*64 + hf*32 + n4*4];
            t2[n4*4+0] += hk*w.x; t2[n4*4+1] += hk*w.y;
            t2[n4*4+2] += hk*w.z; t2[n4*4+3] += hk*w.w;
        }
    }
    __syncthreads();   // all h2 reads done
    #pragma unroll
    for (int n = 0; n < 32; ++n) tc[v][hf*32+n] = t2[n];
    __syncthreads();
    { float p = 0.f;
      for (int r = 0; r < 32; ++r) p += tc[rg2*32+r][rd2];
      part[rg2][rd2] = p; }
    __syncthreads();
    if (tid < 64) S[tid] = part[0][tid]+part[1][tid]+part[2][tid]+part[3][tid];
    __syncthreads();
    float* hrow = hout + (size_t)(b*128 + v)*64 + hf*32;
    #pragma unroll
    for (int n4 = 0; n4 < 8; ++n4) {
        float4 o;
        o.x = (S[hf*32+n4*4+0] - t2[n4*4+0])*GNORM + bb2[hf*32+n4*4+0];
        o.y = (S[hf*32+n4*4+1] - t2[n4*4+1])*GNORM + bb2[hf*32+n4*4+1];
        o.z = (S[hf*32+n4*4+2] - t2[n4*4+2])*GNORM + bb2[hf*32+n4*4+2];
        o.w = (S[hf*32+n4*4+3] - t2[n4*4+3])*GNORM + bb2[hf*32+n4*4+3];
        *(float4*)(hrow + n4*4) = o;
    }
}

// ---------------------------------------------------------------------------
// K2: node MLP; wave-per-node; writes U diagonal blocks
// ---------------------------------------------------------------------------
__global__ __launch_bounds__(256) void k_nodemlp(
    const float* __restrict__ xb,
    const float* __restrict__ Wn0, const float* __restrict__ bn0,
    const float* __restrict__ Wn1, const float* __restrict__ bn1,
    const float* __restrict__ Wn2, const float* __restrict__ bn2,
    float* __restrict__ U)
{
    __shared__ __align__(16) float w0[4096], w1[4096], w2[640];
    __shared__ float bb0[64], bb1[64];
    __shared__ float bb2[16];
    __shared__ float xin[4][64], t1[4][64], t2[4][64], vb[4][10];
    const int tid = threadIdx.x;
    const int wv = tid >> 6, lane = tid & 63;
    const int node = blockIdx.x*4 + wv;

    for (int idx = tid; idx < 1024; idx += 256) {
        ((float4*)w0)[idx] = ((const float4*)Wn0)[idx];
        ((float4*)w1)[idx] = ((const float4*)Wn1)[idx];
    }
    for (int idx = tid; idx < 160; idx += 256)
        ((float4*)w2)[idx] = ((const float4*)Wn2)[idx];
    if (tid < 64) bb0[tid] = bn0[tid];
    else if (tid < 128) bb1[tid-64] = bn1[tid-64];
    else if (tid < 138) bb2[tid-128] = bn2[tid-128];
    xin[wv][lane] = xb[(size_t)node*64 + lane];
    __syncthreads();

    float a = bb0[lane];
    for (int k = 0; k < 64; ++k) a += xin[wv][k]*w0[k*64 + lane];
    t1[wv][lane] = LRELU(a);
    __syncthreads();

    float c = bb1[lane];
    for (int k = 0; k < 64; ++k) c += t1[wv][k]*w1[k*64 + lane];
    t2[wv][lane] = LRELU(c);
    __syncthreads();

    if (lane < 10) {
        float o = bb2[lane];
        for (int k = 0; k < 64; ++k) o += t2[wv][k]*w2[k*10 + lane];
        vb[wv][lane] = o;
    }
    __syncthreads();

    if (lane < 16) {
        const int m = (int)((0x9863875265413210ull >> (4*lane)) & 15ull);
        const int b = node >> 7, i = node & 127;
        U[(size_t)b*262144 + (size_t)(4*i + (lane>>2))*512 + 4*i + (lane&3)] = vb[wv][m];
    }
}

// ---------------------------------------------------------------------------
// K3: A = xb @ We0[0:64,:] + be0 (bias folded), Bt = xb @ We0[64:128,:]
// ---------------------------------------------------------------------------
__global__ __launch_bounds__(256) void k_ab(
    const float* __restrict__ xb,
    const float* __restrict__ We0, const float* __restrict__ be0v,
    float* __restrict__ Aout, float* __restrict__ Bout)
{
    __shared__ float xs[16][64];
    const int tid  = threadIdx.x;
    const int col  = tid & 127, nh = tid >> 7;
    const int base = blockIdx.x * 16;
    for (int idx = tid; idx < 1024; idx += 256)
        xs[idx>>6][idx&63] = xb[(size_t)base*64 + idx];
    __syncthreads();

    float accA[8], accB[8];
    #pragma unroll
    for (int nd = 0; nd < 8; ++nd) { accA[nd] = 0.f; accB[nd] = 0.f; }
    for (int k = 0; k < 64; ++k) {
        const float wa = We0[k*128 + col];
        const float wb = We0[(64+k)*128 + col];
        #pragma unroll
        for (int nd = 0; nd < 8; ++nd) {
            const float xval = xs[nh*8+nd][k];
            accA[nd] += xval*wa;
            accB[nd] += xval*wb;
        }
    }
    const float bias = be0v[col];
    #pragma unroll
    for (int nd = 0; nd < 8; ++nd) {
        Aout[(size_t)(base+nh*8+nd)*128 + col] = accA[nd] + bias;
        Bout[(size_t)(base+nh*8+nd)*128 + col] = accB[nd];
    }
}

// ---------------------------------------------------------------------------
// K4: pre-split We1 (hi/mid bf16) into MFMA B-fragment order, and We2 too.
// ---------------------------------------------------------------------------
__global__ __launch_bounds__(256) void k_prep(
    const float* __restrict__ We1, const float* __restrict__ We2,
    ushort_t* __restrict__ BH, ushort_t* __restrict__ BM,
    ushort_t* __restrict__ W2H, ushort_t* __restrict__ W2M)
{
    const int gid = blockIdx.x*256 + threadIdx.x;
    if (gid < 16384) {
        const int k = gid >> 7, col = gid & 127;
        const float v = We1[gid];
        const ushort_t h = f2bf(v);
        const ushort_t m = f2bf(v - bf2f(h));
        const int cf = col >> 4, kc = (k >> 5) & 3;
        const int ln = ((k >> 3) & 3)*16 + (col & 15);
        const int e  = k & 7;
        const int off = ((cf*4 + kc)*64 + ln)*8 + e;
        BH[off] = h; BM[off] = m;
    }
    const int g2 = gid - 16384;
    if (g2 >= 0 && g2 < 2048) {
        const int k = g2 >> 4, n = g2 & 15;
        const float v = We2[g2];
        const ushort_t h = f2bf(v);
        const ushort_t m = f2bf(v - bf2f(h));
        const int kc = k >> 5;
        const int ln = ((k >> 3) & 3)*16 + n;
        const int e  = k & 7;
        const int off = (kc*64 + ln)*8 + e;
        W2H[off] = h; W2M[off] = m;
    }
}

// ---------------------------------------------------------------------------
// K5: per-edge MLP, fully MFMA (3-product bf16 split ~= fp32 accuracy).
// 4 tiles of 64 edges per WG with cross-tile register prefetch (T14).
// NATURAL WG order (graph-major): robust L2 locality under any bid->XCD
// mapping — the round-4 XCD swizzle destroyed L2 reuse (FETCH 42MB -> 1.1GB).
// LDS 32 KB: eh/em [64]x256B XOR-swizzled; e1 overlays; wave-local epilogue
// transpose scratch inside each wave's own row region.
// ---------------------------------------------------------------------------
__global__ __launch_bounds__(256, 4) void k_edge(
    const float* __restrict__ A, const float* __restrict__ Bt,
    const int* __restrict__ ud,
    const ushort_t* __restrict__ BH, const ushort_t* __restrict__ BM,
    const float* __restrict__ be1v,
    const ushort_t* __restrict__ W2H, const ushort_t* __restrict__ W2M,
    const float* __restrict__ be2v,
    float* __restrict__ U)
{
    __shared__ __align__(16) char smem[32768];
    const int tid = threadIdx.x;
    const int wv = tid >> 6, lane = tid & 63;
    const int wg = blockIdx.x;            // natural order: graph-major
    const int b  = wg >> 5;
    const int w0 = wg & 31;
    const int t0 = 4*w0;
    const int nt = (t0 + 4 <= 127) ? 4 : (127 - t0);

    const float be2  = be2v[lane & 15];
    const float be1c0 = be1v[wv*32 + (lane & 15)];
    const float be1c1 = be1v[wv*32 + 16 + (lane & 15)];
    const float* Ab = A  + (size_t)b*16384;
    const float* Bb = Bt + (size_t)b*16384;
    float* Ub = U + (size_t)b*262144;

    // ---- prefetch tile t0 into registers ----
    float4 pa[8], pb[8];
    {
        const int2 ij1 = *(const int2*)(ud + t0*128 + 2*lane);
        const float4* Ar = (const float4*)(Ab + (size_t)ij1.x*128 + wv*32);
        const float4* Br = (const float4*)(Bb + (size_t)ij1.y*128 + wv*32);
        #pragma unroll
        for (int q = 0; q < 8; ++q) { pa[q] = Ar[q]; pb[q] = Br[q]; }
    }

    for (int ti = 0; ti < nt; ++ti) {
        const int t = t0 + ti;

        // --- phase 1: e0 = lrelu(A'_i + Bt_j); split hi/mid -> LDS swizzled
        {
            const int sw = (lane & 7) << 4;
            char* rowh = smem + lane*256;
            #pragma unroll
            for (int q = 0; q < 4; ++q) {
                const float4 a0 = pa[2*q], a1 = pa[2*q+1];
                const float4 b0 = pb[2*q], b1 = pb[2*q+1];
                float vs[8] = {a0.x+b0.x, a0.y+b0.y, a0.z+b0.z, a0.w+b0.w,
                               a1.x+b1.x, a1.y+b1.y, a1.z+b1.z, a1.w+b1.w};
                ushort_t hb[8], mb[8];
                #pragma unroll
                for (int e = 0; e < 8; ++e) {
                    const float vv = LRELU(vs[e]);
                    const ushort_t h = f2bf(vv);
                    hb[e] = h;
                    mb[e] = f2bf(vv - bf2f(h));
                }
                const int off = (64*wv + 16*q) ^ sw;
                *(s16x8*)(rowh + off)         = *(const s16x8*)hb;
                *(s16x8*)(rowh + 16384 + off) = *(const s16x8*)mb;
            }
        }
        __syncthreads();

        // --- phase 2: e1 = e0 @ We1 (3-product). Wave wv: cols [32wv, 32wv+32)
        f32x4 acc[4][2];
        #pragma unroll
        for (int rf = 0; rf < 4; ++rf) {
            acc[rf][0] = (f32x4){0.f,0.f,0.f,0.f};
            acc[rf][1] = (f32x4){0.f,0.f,0.f,0.f};
        }
        {
            const int arow = lane & 15;
            const int klo  = (lane >> 4) * 16;
            #pragma unroll
            for (int kc = 0; kc < 4; ++kc) {
                const int o0 = (((wv*2 + 0)*4 + kc)*64 + lane)*8;
                const int o1 = (((wv*2 + 1)*4 + kc)*64 + lane)*8;
                const s16x8 bh0 = *(const s16x8*)(BH + o0);
                const s16x8 bm0 = *(const s16x8*)(BM + o0);
                const s16x8 bh1 = *(const s16x8*)(BH + o1);
                const s16x8 bm1 = *(const s16x8*)(BM + o1);
                const int kb = kc*64 + klo;
                #pragma unroll
                for (int rf = 0; rf < 4; ++rf) {
                    const int row = rf*16 + arow;
                    const int off = row*256 + (kb ^ ((row & 7) << 4));
                    const s16x8 ah = *(const s16x8*)(smem + off);
                    const s16x8 am = *(const s16x8*)(smem + 16384 + off);
                    MFMA(acc[rf][0], ah, bh0);
                    MFMA(acc[rf][0], ah, bm0);
                    MFMA(acc[rf][0], am, bh0);
                    MFMA(acc[rf][1], ah, bh1);
                    MFMA(acc[rf][1], ah, bm1);
                    MFMA(acc[rf][1], am, bh1);
                }
            }
        }
        __syncthreads();   // eh/em reads done; safe to overlay e1

        // prefetch next tile's edge indices early (covers VMEM latency)
        int2 ijn;
        const bool more = (ti + 1 < nt);
        if (more) ijn = *(const int2*)(ud + (t+1)*128 + 2*lane);

        // --- e1 = lrelu(acc + be1) split hi/mid, packed (m<<16|h) u32 -> LDS
        {
            const int ccol = lane & 15;
            const int crow = (lane >> 4) * 4;
            #pragma unroll
            for (int c = 0; c < 2; ++c) {
                const float b1 = c ? be1c1 : be1c0;
                const int col4 = (wv*32 + c*16 + ccol)*4;
                #pragma unroll
                for (int rf = 0; rf < 4; ++rf) {
                    #pragma unroll
                    for (int r = 0; r < 4; ++r) {
                        const int row = rf*16 + crow + r;
                        const float v = LRELU(acc[rf][c][r] + b1);
                        const ushort_t h = f2bf(v);
                        const ushort_t m = f2bf(v - bf2f(h));
                        const u32 word = ((u32)m << 16) | (u32)h;
                        *(u32*)(smem + row*512 + (col4 ^ ((row & 7) << 4))) = word;
                    }
                }
            }
        }

        // prefetch next tile's A/Bt rows (latency hidden under phase 3)
        if (more) {
            const float4* Arn = (const float4*)(Ab + (size_t)ijn.x*128 + wv*32);
            const float4* Brn = (const float4*)(Bb + (size_t)ijn.y*128 + wv*32);
            #pragma unroll
            for (int q = 0; q < 8; ++q) { pa[q] = Arn[q]; pb[q] = Brn[q]; }
        }
        // We2 fragments (L2-hot; issued before barrier, consumed in phase 3)
        s16x8 w2h[4], w2m[4];
        #pragma unroll
        for (int kc = 0; kc < 4; ++kc) {
            const int woff = (kc*64 + lane)*8;
            w2h[kc] = *(const s16x8*)(W2H + woff);
            w2m[kc] = *(const s16x8*)(W2M + woff);
        }
        __syncthreads();

        // --- phase 3: e2 = e1 @ We2 + be2 via MFMA; wave wv: rows [16wv,+16)
        {
            const int row = wv*16 + (lane & 15);
            const int swr = (row & 7) << 4;
            const char* rb = smem + row*512;
            f32x4 acc2 = (f32x4){0.f,0.f,0.f,0.f};
            #pragma unroll
            for (int kc = 0; kc < 4; ++kc) {
                const int kb = kc*128 + (lane >> 4)*32;
                const i32x4 wd0 = *(const i32x4*)(rb + (kb ^ swr));
                const i32x4 wd1 = *(const i32x4*)(rb + ((kb + 16) ^ swr));
                i32x4 hv, mv;
                hv[0] = (int)__builtin_amdgcn_perm((u32)wd0[1], (u32)wd0[0], 0x05040100u);
                hv[1] = (int)__builtin_amdgcn_perm((u32)wd0[3], (u32)wd0[2], 0x05040100u);
                hv[2] = (int)__builtin_amdgcn_perm((u32)wd1[1], (u32)wd1[0], 0x05040100u);
                hv[3] = (int)__builtin_amdgcn_perm((u32)wd1[3], (u32)wd1[2], 0x05040100u);
                mv[0] = (int)__builtin_amdgcn_perm((u32)wd0[1], (u32)wd0[0], 0x07060302u);
                mv[1] = (int)__builtin_amdgcn_perm((u32)wd0[3], (u32)wd0[2], 0x07060302u);
                mv[2] = (int)__builtin_amdgcn_perm((u32)wd1[1], (u32)wd1[0], 0x07060302u);
                mv[3] = (int)__builtin_amdgcn_perm((u32)wd1[3], (u32)wd1[2], 0x07060302u);
                const s16x8 ah = __builtin_bit_cast(s16x8, hv);
                const s16x8 am = __builtin_bit_cast(s16x8, mv);
                MFMA(acc2, ah, w2h[kc]);
                MFMA(acc2, ah, w2m[kc]);
                MFMA(acc2, am, w2h[kc]);
            }

            // epilogue: wave-local transpose (stride-80 rows) -> float4 stores
            const int sloc = lane >> 2;         // edge within wave's 16
            const int p    = lane & 3;          // sub-row of 4x4 block
            const int2 ij3 = *(const int2*)(ud + t*128 + 2*(wv*16 + sloc));
            char* scr = smem + wv*8192;         // wave-own region (rows done)
            const int c16 = lane & 15, hi = lane >> 4;
            #pragma unroll
            for (int r = 0; r < 4; ++r)
                *(float*)(scr + (hi*4 + r)*80 + c16*4) = acc2[r] + be2;
            const f32x4 rv = *(const f32x4*)(scr + sloc*80 + p*16);
            float4 o; o.x = rv[0]; o.y = rv[1]; o.z = rv[2]; o.w = rv[3];
            *(float4*)(Ub + (size_t)(4*ij3.x + p)*512 + 4*ij3.y) = o;
            *(float4*)(Ub + (size_t)(4*ij3.y + p)*512 + 4*ij3.x) = o;
        }
        __syncthreads();   // epilogue LDS reads done before next phase 1
    }
}

// ---------------------------------------------------------------------------
extern "C" void kernel_launch(void* const* d_in, const int* in_sizes, int n_in,
                              void* d_out, int out_size, void* d_ws, size_t ws_size,
                              hipStream_t stream)
{
    const float* x   = (const float*)d_in[0];
    const int*   ud  = (const int*)  d_in[3];
    const float* Wg0 = (const float*)d_in[4];
    const float* bg0 = (const float*)d_in[5];
    const float* Wg1 = (const float*)d_in[6];
    const float* bg1 = (const float*)d_in[7];
    const float* Wg2 = (const float*)d_in[8];
    const float* bg2 = (const float*)d_in[9];
    const float* Wn0 = (const float*)d_in[10];
    const float* bn0 = (const float*)d_in[11];
    const float* Wn1 = (const float*)d_in[12];
    const float* bn1 = (const float*)d_in[13];
    const float* Wn2 = (const float*)d_in[14];
    const float* bn2 = (const float*)d_in[15];
    const float* We0 = (const float*)d_in[16];
    const float* be0 = (const float*)d_in[17];
    const float* We1 = (const float*)d_in[18];
    const float* be1 = (const float*)d_in[19];
    const float* We2 = (const float*)d_in[20];
    const float* be2 = (const float*)d_in[21];

    float* hout = (float*)d_out;                 // (16384, 64) == xb
    float* U    = (float*)d_out + 1048576;       // (128, 512, 512)
    float* Aw   = (float*)d_ws;                  // (16384, 128)  A + be0
    float* Bw   = Aw + (size_t)16384*128;        // (16384, 128)
    ushort_t* BH  = (ushort_t*)((char*)d_ws + (size_t)2*16384*128*4);
    ushort_t* BM  = BH + 16384;
    ushort_t* W2H = BM + 16384;
    ushort_t* W2M = W2H + 2048;

    k_prep<<<dim3(72), dim3(256), 0, stream>>>(We1, We2, BH, BM, W2H, W2M);
    k_gcn<<<dim3(128), dim3(256), 0, stream>>>(x, Wg0,bg0, Wg1,bg1, Wg2,bg2, hout);
    k_ab<<<dim3(1024), dim3(256), 0, stream>>>(hout, We0, be0, Aw, Bw);
    k_edge<<<dim3(4096), dim3(256), 0, stream>>>(Aw, Bw, ud,
                                                 BH, BM, be1, W2H, W2M, be2, U);
    k_nodemlp<<<dim3(4096), dim3(256), 0, stream>>>(hout, Wn0,bn0, Wn1,bn1, Wn2,bn2, U);
}

// Round 7
// 359.020 us; speedup vs baseline: 2.6886x; 2.6886x over previous
//
#include <hip/hip_runtime.h>
#include <hip/hip_bf16.h>

#define LRELU(v) ((v) >= 0.f ? (v) : 0.1f*(v))

typedef float  f32x4 __attribute__((ext_vector_type(4)));
typedef short  s16x8 __attribute__((ext_vector_type(8)));
typedef int    i32x4 __attribute__((ext_vector_type(4)));
typedef unsigned short ushort_t;
typedef unsigned int   u32;

constexpr float GNORM = 1.0f/127.0f;  // dinv[src]*dinv[dst] on complete graph

#define MFMA(d, a, b) d = __builtin_amdgcn_mfma_f32_16x16x32_bf16(a, b, d, 0, 0, 0)

__device__ __forceinline__ ushort_t f2bf(float v) {
    return __builtin_bit_cast(ushort_t, __float2bfloat16(v));
}
__device__ __forceinline__ float bf2f(ushort_t u) {
    return __builtin_bit_cast(float, (u32)u << 16);
}

// ---------------------------------------------------------------------------
// K1: GCN closed form (complete graph): out_v = (S - (hW)_v)/127 + b
// ---------------------------------------------------------------------------
__global__ __launch_bounds__(256) void k_gcn(
    const float* __restrict__ x,
    const float* __restrict__ Wg0, const float* __restrict__ bg0,
    const float* __restrict__ Wg1, const float* __restrict__ bg1,
    const float* __restrict__ Wg2, const float* __restrict__ bg2,
    float* __restrict__ hout)
{
    __shared__ __align__(16) float w0[192], w1[1024], w2[2048];
    __shared__ float bb0[32], bb1[32], bb2[64];
    __shared__ float ta[128][33];
    __shared__ float tc[128][65];
    __shared__ float part[8][64];
    __shared__ float S[64];
    const int tid = threadIdx.x;
    const int v = tid & 127, hf = tid >> 7;
    const int b = blockIdx.x;

    for (int idx = tid; idx < 192;  idx += 256) w0[idx] = Wg0[idx];
    for (int idx = tid; idx < 1024; idx += 256) w1[idx] = Wg1[idx];
    for (int idx = tid; idx < 2048; idx += 256) w2[idx] = Wg2[idx];
    if (tid < 32) { bb0[tid] = bg0[tid]; bb1[tid] = bg1[tid]; }
    if (tid >= 64 && tid < 128) bb2[tid-64] = bg2[tid-64];

    float xv[6];
    #pragma unroll
    for (int k = 0; k < 6; ++k) xv[k] = x[(b*128 + v)*6 + k];
    __syncthreads();

    const int rg = tid >> 5, rd = tid & 31;
    const int rg2 = tid >> 6, rd2 = tid & 63;

    // ---- layer 0: 6 -> 32 ----
    float t0[16];
    #pragma unroll
    for (int n = 0; n < 16; ++n) {
        float a = 0.f;
        #pragma unroll
        for (int k = 0; k < 6; ++k) a += xv[k]*w0[k*32 + hf*16 + n];
        t0[n] = a; ta[v][hf*16+n] = a;
    }
    __syncthreads();
    { float p = 0.f;
      for (int r = 0; r < 16; ++r) p += ta[rg*16+r][rd];
      part[rg][rd] = p; }
    __syncthreads();
    if (tid < 32) S[tid] = part[0][tid]+part[1][tid]+part[2][tid]+part[3][tid]
                          +part[4][tid]+part[5][tid]+part[6][tid]+part[7][tid];
    __syncthreads();
    float h1[16];
    #pragma unroll
    for (int n = 0; n < 16; ++n) {
        float hv = (S[hf*16+n] - t0[n])*GNORM + bb0[hf*16+n];
        h1[n] = LRELU(hv);
        ta[v][hf*16+n] = h1[n];
    }
    __syncthreads();

    // ---- layer 1: 32 -> 32 ----
    float t1[16];
    #pragma unroll
    for (int n = 0; n < 16; ++n) t1[n] = 0.f;
    for (int k = 0; k < 32; ++k) {
        const float hk = ta[v][k];
        #pragma unroll
        for (int n4 = 0; n4 < 4; ++n4) {
            const float4 w = *(const float4*)&w1[k*32 + hf*16 + n4*4];
            t1[n4*4+0] += hk*w.x; t1[n4*4+1] += hk*w.y;
            t1[n4*4+2] += hk*w.z; t1[n4*4+3] += hk*w.w;
        }
    }
    __syncthreads();
    #pragma unroll
    for (int n = 0; n < 16; ++n) ta[v][hf*16+n] = t1[n];
    __syncthreads();
    { float p = 0.f;
      for (int r = 0; r < 16; ++r) p += ta[rg*16+r][rd];
      part[rg][rd] = p; }
    __syncthreads();
    if (tid < 32) S[tid] = part[0][tid]+part[1][tid]+part[2][tid]+part[3][tid]
                          +part[4][tid]+part[5][tid]+part[6][tid]+part[7][tid];
    __syncthreads();
    float h2[16];
    #pragma unroll
    for (int n = 0; n < 16; ++n) {
        float hv = (S[hf*16+n] - t1[n])*GNORM + bb1[hf*16+n];
        h2[n] = LRELU(hv);
        ta[v][hf*16+n] = h2[n];
    }
    __syncthreads();

    // ---- layer 2: 32 -> 64 ----
    float t2[32];
    #pragma unroll
    for (int n = 0; n < 32; ++n) t2[n] = 0.f;
    for (int k = 0; k < 32; ++k) {
        const float hk = ta[v][k];
        #pragma unroll
        for (int n4 = 0; n4 < 8; ++n4) {
            const float4 w = *(const float4*)&w2[k*64 + hf*32 + n4*4];
            t2[n4*4+0] += hk*w.x; t2[n4*4+1] += hk*w.y;
            t2[n4*4+2] += hk*w.z; t2[n4*4+3] += hk*w.w;
        }
    }
    __syncthreads();
    #pragma unroll
    for (int n = 0; n < 32; ++n) tc[v][hf*32+n] = t2[n];
    __syncthreads();
    { float p = 0.f;
      for (int r = 0; r < 32; ++r) p += tc[rg2*32+r][rd2];
      part[rg2][rd2] = p; }
    __syncthreads();
    if (tid < 64) S[tid] = part[0][tid]+part[1][tid]+part[2][tid]+part[3][tid];
    __syncthreads();
    float* hrow = hout + (size_t)(b*128 + v)*64 + hf*32;
    #pragma unroll
    for (int n4 = 0; n4 < 8; ++n4) {
        float4 o;
        o.x = (S[hf*32+n4*4+0] - t2[n4*4+0])*GNORM + bb2[hf*32+n4*4+0];
        o.y = (S[hf*32+n4*4+1] - t2[n4*4+1])*GNORM + bb2[hf*32+n4*4+1];
        o.z = (S[hf*32+n4*4+2] - t2[n4*4+2])*GNORM + bb2[hf*32+n4*4+2];
        o.w = (S[hf*32+n4*4+3] - t2[n4*4+3])*GNORM + bb2[hf*32+n4*4+3];
        *(float4*)(hrow + n4*4) = o;
    }
}

// ---------------------------------------------------------------------------
// K2: node MLP; 8 nodes per WG (2 per wave, ILP-2); writes U diagonal blocks
// ---------------------------------------------------------------------------
__global__ __launch_bounds__(256) void k_nodemlp(
    const float* __restrict__ xb,
    const float* __restrict__ Wn0, const float* __restrict__ bn0,
    const float* __restrict__ Wn1, const float* __restrict__ bn1,
    const float* __restrict__ Wn2, const float* __restrict__ bn2,
    float* __restrict__ U)
{
    __shared__ __align__(16) float w0[4096], w1[4096], w2[640];
    __shared__ float bb0[64], bb1[64];
    __shared__ float bb2[16];
    __shared__ float xin[8][64], t1[8][64], t2[8][64], vb[8][10];
    const int tid = threadIdx.x;
    const int wv = tid >> 6, lane = tid & 63;
    const int n0 = blockIdx.x*8 + wv*2;     // wave handles nodes n0, n0+1

    for (int idx = tid; idx < 1024; idx += 256) {
        ((float4*)w0)[idx] = ((const float4*)Wn0)[idx];
        ((float4*)w1)[idx] = ((const float4*)Wn1)[idx];
    }
    for (int idx = tid; idx < 160; idx += 256)
        ((float4*)w2)[idx] = ((const float4*)Wn2)[idx];
    if (tid < 64) bb0[tid] = bn0[tid];
    else if (tid < 128) bb1[tid-64] = bn1[tid-64];
    else if (tid < 138) bb2[tid-128] = bn2[tid-128];
    xin[wv*2+0][lane] = xb[(size_t)(n0+0)*64 + lane];
    xin[wv*2+1][lane] = xb[(size_t)(n0+1)*64 + lane];
    __syncthreads();

    float a0 = bb0[lane], a1 = bb0[lane];
    for (int k = 0; k < 64; ++k) {
        const float w = w0[k*64 + lane];
        a0 += xin[wv*2+0][k]*w;
        a1 += xin[wv*2+1][k]*w;
    }
    t1[wv*2+0][lane] = LRELU(a0);
    t1[wv*2+1][lane] = LRELU(a1);
    __syncthreads();

    float c0 = bb1[lane], c1 = bb1[lane];
    for (int k = 0; k < 64; ++k) {
        const float w = w1[k*64 + lane];
        c0 += t1[wv*2+0][k]*w;
        c1 += t1[wv*2+1][k]*w;
    }
    t2[wv*2+0][lane] = LRELU(c0);
    t2[wv*2+1][lane] = LRELU(c1);
    __syncthreads();

    if (lane < 10) {
        float o0 = bb2[lane], o1 = bb2[lane];
        for (int k = 0; k < 64; ++k) {
            const float w = w2[k*10 + lane];
            o0 += t2[wv*2+0][k]*w;
            o1 += t2[wv*2+1][k]*w;
        }
        vb[wv*2+0][lane] = o0;
        vb[wv*2+1][lane] = o1;
    }
    __syncthreads();

    if (lane < 32) {
        const int nn = n0 + (lane >> 4);
        const int l16 = lane & 15;
        const int m = (int)((0x9863875265413210ull >> (4*l16)) & 15ull);
        const int b = nn >> 7, i = nn & 127;
        U[(size_t)b*262144 + (size_t)(4*i + (l16>>2))*512 + 4*i + (l16&3)]
            = vb[wv*2 + (lane>>4)][m];
    }
}

// ---------------------------------------------------------------------------
// K3 (fused): blocks [0,1024): A = xb@We0[0:64]+be0, Bt = xb@We0[64:128]
//             blocks [1024,1096): pre-split We1/We2 into MFMA B-frag order
// ---------------------------------------------------------------------------
__global__ __launch_bounds__(256) void k_ab_prep(
    const float* __restrict__ xb,
    const float* __restrict__ We0, const float* __restrict__ be0v,
    const float* __restrict__ We1, const float* __restrict__ We2,
    float* __restrict__ Aout, float* __restrict__ Bout,
    ushort_t* __restrict__ BH, ushort_t* __restrict__ BM,
    ushort_t* __restrict__ W2H, ushort_t* __restrict__ W2M)
{
    const int tid = threadIdx.x;
    if (blockIdx.x >= 1024) {
        const int gid = (blockIdx.x - 1024)*256 + tid;
        if (gid < 16384) {
            const int k = gid >> 7, col = gid & 127;
            const float v = We1[gid];
            const ushort_t h = f2bf(v);
            const ushort_t m = f2bf(v - bf2f(h));
            const int cf = col >> 4, kc = (k >> 5) & 3;
            const int ln = ((k >> 3) & 3)*16 + (col & 15);
            const int e  = k & 7;
            const int off = ((cf*4 + kc)*64 + ln)*8 + e;
            BH[off] = h; BM[off] = m;
        }
        const int g2 = gid - 16384;
        if (g2 >= 0 && g2 < 2048) {
            const int k = g2 >> 4, n = g2 & 15;
            const float v = We2[g2];
            const ushort_t h = f2bf(v);
            const ushort_t m = f2bf(v - bf2f(h));
            const int kc = k >> 5;
            const int ln = ((k >> 3) & 3)*16 + n;
            const int e  = k & 7;
            const int off = (kc*64 + ln)*8 + e;
            W2H[off] = h; W2M[off] = m;
        }
        return;
    }

    __shared__ float xs[16][64];
    const int col  = tid & 127, nh = tid >> 7;
    const int base = blockIdx.x * 16;
    for (int idx = tid; idx < 1024; idx += 256)
        xs[idx>>6][idx&63] = xb[(size_t)base*64 + idx];
    __syncthreads();

    float accA[8], accB[8];
    #pragma unroll
    for (int nd = 0; nd < 8; ++nd) { accA[nd] = 0.f; accB[nd] = 0.f; }
    for (int k = 0; k < 64; ++k) {
        const float wa = We0[k*128 + col];
        const float wb = We0[(64+k)*128 + col];
        #pragma unroll
        for (int nd = 0; nd < 8; ++nd) {
            const float xval = xs[nh*8+nd][k];
            accA[nd] += xval*wa;
            accB[nd] += xval*wb;
        }
    }
    const float bias = be0v[col];
    #pragma unroll
    for (int nd = 0; nd < 8; ++nd) {
        Aout[(size_t)(base+nh*8+nd)*128 + col] = accA[nd] + bias;
        Bout[(size_t)(base+nh*8+nd)*128 + col] = accB[nd];
    }
}

// ---------------------------------------------------------------------------
// K5: per-edge MLP by NODE-BLOCK PAIRS. WG = (graph, 16x16 block pair):
// 256 edges, reads only 16+16 A/Bt rows (16 KB) staged in LDS fp32 —
// structural 8-16x read reduction, no L2 dependence. We1 B-frags hoisted to
// registers across the 4 sub-tiles. Inner 3-phase pipeline = round-3 proven.
// Diagonal block pairs mask stores to i<j. Mirror stores complete full 64B
// lines within the WG (same wave covers 4 consecutive i across sub-tiles).
// LDS: [0,32K) eh/em (overlaid by e1 + epilogue scratch); [32K,+16.9K) A/B fp32.
// ---------------------------------------------------------------------------
__global__ __launch_bounds__(256, 3) void k_edge(
    const float* __restrict__ A, const float* __restrict__ Bt,
    const ushort_t* __restrict__ BH, const ushort_t* __restrict__ BM,
    const float* __restrict__ be1v,
    const ushort_t* __restrict__ W2H, const ushort_t* __restrict__ W2M,
    const float* __restrict__ be2v,
    float* __restrict__ U)
{
    __shared__ __align__(16) char smem[32768 + 16896];
    float* Afp = (float*)(smem + 32768);           // [16][132]
    float* Bfp = (float*)(smem + 32768 + 8448);    // [16][132]

    const int tid = threadIdx.x;
    const int wv = tid >> 6, lane = tid & 63;
    const int wg = blockIdx.x;
    const int b  = wg / 36;
    int rem = wg - b*36;
    int bi = 0;
    while (rem >= 8 - bi) { rem -= 8 - bi; ++bi; }
    const int bj = bi + rem;
    const bool diag = (bi == bj);

    // ---- stage A-block (+be0 folded) and B-block fp32 into LDS ----
    {
        const float4* Ag = (const float4*)(A  + (size_t)(b*128 + bi*16)*128);
        const float4* Bg = (const float4*)(Bt + (size_t)(b*128 + bj*16)*128);
        #pragma unroll
        for (int q = 0; q < 2; ++q) {
            const int f = tid + 256*q;
            const int r = f >> 5, c = f & 31;
            *(float4*)(Afp + r*132 + c*4) = Ag[f];
            *(float4*)(Bfp + r*132 + c*4) = Bg[f];
        }
    }

    // ---- hoist We1 B-fragments into registers (reused by all 4 sub-tiles) ----
    s16x8 bh0[4], bm0[4], bh1[4], bm1[4];
    #pragma unroll
    for (int kc = 0; kc < 4; ++kc) {
        const int o0 = (((wv*2 + 0)*4 + kc)*64 + lane)*8;
        const int o1 = (((wv*2 + 1)*4 + kc)*64 + lane)*8;
        bh0[kc] = *(const s16x8*)(BH + o0);
        bm0[kc] = *(const s16x8*)(BM + o0);
        bh1[kc] = *(const s16x8*)(BH + o1);
        bm1[kc] = *(const s16x8*)(BM + o1);
    }
    const float be2  = be2v[lane & 15];
    const float be1c0 = be1v[wv*32 + (lane & 15)];
    const float be1c1 = be1v[wv*32 + 16 + (lane & 15)];
    float* Ub = U + (size_t)b*262144;
    __syncthreads();

    #pragma unroll
    for (int st = 0; st < 4; ++st) {
        // --- phase 1: edge s=lane: iloc = 4st+(lane>>4), j = lane&15,
        //     cols [32wv,32wv+32): e0 = lrelu(A'[iloc]+B[j]) -> hi/mid LDS
        {
            const int iloc = 4*st + (lane >> 4);
            const int jloc = lane & 15;
            const float* ar = Afp + iloc*132 + wv*32;
            const float* br = Bfp + jloc*132 + wv*32;
            const int sw = (lane & 7) << 4;
            char* rowh = smem + lane*256;
            #pragma unroll
            for (int q = 0; q < 4; ++q) {
                const float4 a0 = *(const float4*)(ar + 8*q);
                const float4 a1 = *(const float4*)(ar + 8*q + 4);
                const float4 b0 = *(const float4*)(br + 8*q);
                const float4 b1 = *(const float4*)(br + 8*q + 4);
                float vs[8] = {a0.x+b0.x, a0.y+b0.y, a0.z+b0.z, a0.w+b0.w,
                               a1.x+b1.x, a1.y+b1.y, a1.z+b1.z, a1.w+b1.w};
                ushort_t hb[8], mb[8];
                #pragma unroll
                for (int e = 0; e < 8; ++e) {
                    const float vv = LRELU(vs[e]);
                    const ushort_t h = f2bf(vv);
                    hb[e] = h;
                    mb[e] = f2bf(vv - bf2f(h));
                }
                const int off = (64*wv + 16*q) ^ sw;
                *(s16x8*)(rowh + off)         = *(const s16x8*)hb;
                *(s16x8*)(rowh + 16384 + off) = *(const s16x8*)mb;
            }
        }
        __syncthreads();

        // --- phase 2: e1 = e0 @ We1 (3-product); wave wv: cols [32wv,+32)
        f32x4 acc[4][2];
        #pragma unroll
        for (int rf = 0; rf < 4; ++rf) {
            acc[rf][0] = (f32x4){0.f,0.f,0.f,0.f};
            acc[rf][1] = (f32x4){0.f,0.f,0.f,0.f};
        }
        {
            const int arow = lane & 15;
            const int klo  = (lane >> 4) * 16;
            #pragma unroll
            for (int kc = 0; kc < 4; ++kc) {
                const int kb = kc*64 + klo;
                #pragma unroll
                for (int rf = 0; rf < 4; ++rf) {
                    const int row = rf*16 + arow;
                    const int off = row*256 + (kb ^ ((row & 7) << 4));
                    const s16x8 ah = *(const s16x8*)(smem + off);
                    const s16x8 am = *(const s16x8*)(smem + 16384 + off);
                    MFMA(acc[rf][0], ah, bh0[kc]);
                    MFMA(acc[rf][0], ah, bm0[kc]);
                    MFMA(acc[rf][0], am, bh0[kc]);
                    MFMA(acc[rf][1], ah, bh1[kc]);
                    MFMA(acc[rf][1], ah, bm1[kc]);
                    MFMA(acc[rf][1], am, bh1[kc]);
                }
            }
        }
        __syncthreads();   // eh/em reads done; safe to overlay e1

        // --- e1 = lrelu(acc + be1) split hi/mid, packed (m<<16|h) -> LDS
        {
            const int ccol = lane & 15;
            const int crow = (lane >> 4) * 4;
            #pragma unroll
            for (int c = 0; c < 2; ++c) {
                const float b1 = c ? be1c1 : be1c0;
                const int col4 = (wv*32 + c*16 + ccol)*4;
                #pragma unroll
                for (int rf = 0; rf < 4; ++rf) {
                    #pragma unroll
                    for (int r = 0; r < 4; ++r) {
                        const int row = rf*16 + crow + r;
                        const float v = LRELU(acc[rf][c][r] + b1);
                        const ushort_t h = f2bf(v);
                        const ushort_t m = f2bf(v - bf2f(h));
                        const u32 word = ((u32)m << 16) | (u32)h;
                        *(u32*)(smem + row*512 + (col4 ^ ((row & 7) << 4))) = word;
                    }
                }
            }
        }
        // We2 fragments (tiny, L2-hot)
        s16x8 w2h[4], w2m[4];
        #pragma unroll
        for (int kc = 0; kc < 4; ++kc) {
            const int woff = (kc*64 + lane)*8;
            w2h[kc] = *(const s16x8*)(W2H + woff);
            w2m[kc] = *(const s16x8*)(W2M + woff);
        }
        __syncthreads();

        // --- phase 3: e2 = e1 @ We2 + be2; wave wv owns rows [16wv,+16)
        {
            const int row = wv*16 + (lane & 15);
            const int swr = (row & 7) << 4;
            const char* rb = smem + row*512;
            f32x4 acc2 = (f32x4){0.f,0.f,0.f,0.f};
            #pragma unroll
            for (int kc = 0; kc < 4; ++kc) {
                const int kb = kc*128 + (lane >> 4)*32;
                const i32x4 wd0 = *(const i32x4*)(rb + (kb ^ swr));
                const i32x4 wd1 = *(const i32x4*)(rb + ((kb + 16) ^ swr));
                i32x4 hv, mv;
                hv[0] = (int)__builtin_amdgcn_perm((u32)wd0[1], (u32)wd0[0], 0x05040100u);
                hv[1] = (int)__builtin_amdgcn_perm((u32)wd0[3], (u32)wd0[2], 0x05040100u);
                hv[2] = (int)__builtin_amdgcn_perm((u32)wd1[1], (u32)wd1[0], 0x05040100u);
                hv[3] = (int)__builtin_amdgcn_perm((u32)wd1[3], (u32)wd1[2], 0x05040100u);
                mv[0] = (int)__builtin_amdgcn_perm((u32)wd0[1], (u32)wd0[0], 0x07060302u);
                mv[1] = (int)__builtin_amdgcn_perm((u32)wd0[3], (u32)wd0[2], 0x07060302u);
                mv[2] = (int)__builtin_amdgcn_perm((u32)wd1[1], (u32)wd1[0], 0x07060302u);
                mv[3] = (int)__builtin_amdgcn_perm((u32)wd1[3], (u32)wd1[2], 0x07060302u);
                const s16x8 ah = __builtin_bit_cast(s16x8, hv);
                const s16x8 am = __builtin_bit_cast(s16x8, mv);
                MFMA(acc2, ah, w2h[kc]);
                MFMA(acc2, ah, w2m[kc]);
                MFMA(acc2, am, w2h[kc]);
            }

            // epilogue: wave-local transpose -> float4 stores (+ mirror)
            char* scr = smem + wv*8192;
            const int c16 = lane & 15, hi = lane >> 4;
            #pragma unroll
            for (int r = 0; r < 4; ++r)
                *(float*)(scr + (hi*4 + r)*80 + c16*4) = acc2[r] + be2;
            const int sloc = lane >> 2;          // j within block (0..15)
            const int pp   = lane & 3;
            const f32x4 rv = *(const f32x4*)(scr + sloc*80 + pp*16);
            float4 o; o.x = rv[0]; o.y = rv[1]; o.z = rv[2]; o.w = rv[3];
            const int il = 4*st + wv;            // i within block (single per wave)
            if (!diag || il < sloc) {
                const int ig = bi*16 + il;
                const int jg = bj*16 + sloc;
                *(float4*)(Ub + (size_t)(4*ig + pp)*512 + 4*jg) = o;
                *(float4*)(Ub + (size_t)(4*jg + pp)*512 + 4*ig) = o;
            }
        }
        __syncthreads();   // epilogue LDS reads done before next phase 1
    }
}

// ---------------------------------------------------------------------------
extern "C" void kernel_launch(void* const* d_in, const int* in_sizes, int n_in,
                              void* d_out, int out_size, void* d_ws, size_t ws_size,
                              hipStream_t stream)
{
    const float* x   = (const float*)d_in[0];
    const float* Wg0 = (const float*)d_in[4];
    const float* bg0 = (const float*)d_in[5];
    const float* Wg1 = (const float*)d_in[6];
    const float* bg1 = (const float*)d_in[7];
    const float* Wg2 = (const float*)d_in[8];
    const float* bg2 = (const float*)d_in[9];
    const float* Wn0 = (const float*)d_in[10];
    const float* bn0 = (const float*)d_in[11];
    const float* Wn1 = (const float*)d_in[12];
    const float* bn1 = (const float*)d_in[13];
    const float* Wn2 = (const float*)d_in[14];
    const float* bn2 = (const float*)d_in[15];
    const float* We0 = (const float*)d_in[16];
    const float* be0 = (const float*)d_in[17];
    const float* We1 = (const float*)d_in[18];
    const float* be1 = (const float*)d_in[19];
    const float* We2 = (const float*)d_in[20];
    const float* be2 = (const float*)d_in[21];

    float* hout = (float*)d_out;                 // (16384, 64) == xb
    float* U    = (float*)d_out + 1048576;       // (128, 512, 512)
    float* Aw   = (float*)d_ws;                  // (16384, 128)  A + be0
    float* Bw   = Aw + (size_t)16384*128;        // (16384, 128)
    ushort_t* BH  = (ushort_t*)((char*)d_ws + (size_t)2*16384*128*4);
    ushort_t* BM  = BH + 16384;
    ushort_t* W2H = BM + 16384;
    ushort_t* W2M = W2H + 2048;

    k_gcn<<<dim3(128), dim3(256), 0, stream>>>(x, Wg0,bg0, Wg1,bg1, Wg2,bg2, hout);
    k_ab_prep<<<dim3(1096), dim3(256), 0, stream>>>(hout, We0, be0, We1, We2,
                                                    Aw, Bw, BH, BM, W2H, W2M);
    k_edge<<<dim3(128*36), dim3(256), 0, stream>>>(Aw, Bw, BH, BM, be1,
                                                   W2H, W2M, be2, U);
    k_nodemlp<<<dim3(2048), dim3(256), 0, stream>>>(hout, Wn0,bn0, Wn1,bn1, Wn2,bn2, U);
}